// Round 10
// baseline (528.947 us; speedup 1.0000x reference)
//
#include <hip/hip_runtime.h>

namespace {

constexpr int T = 1024;
constexpr int B = 1024;
constexpr int L = 10;
constexpr int H = 10;
constexpr int NTHREADS = 128;      // 2 waves: wave0 = layers 0-5, wave1 = layers 6-9
constexpr int U = 4;               // timesteps per interval
constexpr int NWIN = T / U;        // 256 windows
constexpr int NINT = NWIN + L - 1; // 265 intervals
constexpr int BH = B * H;
constexpr int ROWP = 12;           // compact row: 10 real floats + 2 pad (48 B)

using v2f = __attribute__((ext_vector_type(2))) float;
using v4f = __attribute__((ext_vector_type(4))) float;

__device__ __forceinline__ v2f v2fma(v2f a, v2f b, v2f c) {
    return __builtin_elementwise_fma(a, b, c);   // v_pk_fma_f32
}
__device__ __forceinline__ void pin2(v2f& v) { asm volatile("" : "+v"(v)); }
__device__ __forceinline__ float rcp_f(float x) { return __builtin_amdgcn_rcpf(x); }
// bare v_exp_f32 (2^x) - weights are pre-scaled by +/-log2e so no mul needed
__device__ __forceinline__ float exp2_f(float x) {
    float r; asm("v_exp_f32 %0, %1" : "=v"(r) : "v"(x)); return r;
}
__device__ __forceinline__ v2f lo2(v4f q) { return __builtin_shufflevector(q, q, 0, 1); }
__device__ __forceinline__ v2f hi2(v4f q) { return __builtin_shufflevector(q, q, 2, 3); }
#define LDS_FENCE asm volatile("" ::: "memory")

__global__
__attribute__((amdgpu_flat_work_group_size(NTHREADS, NTHREADS)))
__attribute__((amdgpu_waves_per_eu(2)))   // cap VGPR at 256; 2 waves/SIMD resident
void lstm_pipeline(const float* __restrict__ x,    // [T,B,H]
                   const float* __restrict__ hp,   // [L,B,H]
                   const float* __restrict__ cp,   // [L,B,H]
                   const float* __restrict__ Wih,  // [L,4H,H]
                   const float* __restrict__ Whh,  // [L,4H,H]
                   const float* __restrict__ bih,  // [L,4H]
                   const float* __restrict__ bhh,  // [L,4H]
                   float* __restrict__ out,        // [T,B,H]
                   float* __restrict__ hn,         // [L,B,H]
                   float* __restrict__ cn)         // [L,B,H]
{
    // [parity][u][row][compact]; row r = input of layer r (r=0: x, r=l+1:
    // layer-l output). 12-float row stride: layer groups hit disjoint banks.
    __shared__ __align__(16) float buf[2][U][L + 1][ROWP];   // 4224 B

    const int tid = threadIdx.x;
    const int wv = tid >> 6;
    const int ln = tid & 63;
    // (l,j) mapping, proven in prior rounds. Dup lanes repeat valid items of
    // the same wave -> identical values/addresses, benign.
    int lidx;
    if (wv == 0) lidx = (ln < 60) ? ln : (ln - 10);              // dup l=5,j=0..3
    else         lidx = (ln < 40) ? (60 + ln) : (90 + (ln - 40) % 10);  // dup l=9
    const int l = lidx / 10;
    const int j = lidx % 10;
    const int b = blockIdx.x;
    const int boff = b * H + j;

    // ---- weights -> registers, k-pair packed, exp2-prescaled per gate ----
    // wi[g][p] = (W[g-row, 2p], W[g-row, 2p+1]) * scale_g.
    // Gate order g = 0:i 1:f 2:g 3:o; scales: i,f,o -> -log2e, g -> -2*log2e.
    const float NL2E = -1.44269504088896340736f;
    v2f wi[4][5], wh[4][5], bias[4];
    {
        const float* WiL = Wih + (size_t)l * 4 * H * H;
        const float* WhL = Whh + (size_t)l * 4 * H * H;
        const int bo = l * 4 * H;
        #pragma unroll
        for (int g = 0; g < 4; ++g) {
            const float s = (g == 2) ? 2.0f * NL2E : NL2E;
            const float* wr = WiL + (size_t)(g * H + j) * H;
            const float* hr = WhL + (size_t)(g * H + j) * H;
            #pragma unroll
            for (int p = 0; p < 5; ++p) {
                wi[g][p][0] = wr[2 * p] * s; wi[g][p][1] = wr[2 * p + 1] * s;
                wh[g][p][0] = hr[2 * p] * s; wh[g][p][1] = hr[2 * p + 1] * s;
            }
            bias[g][0] = (bih[bo + g * H + j] + bhh[bo + g * H + j]) * s;
            bias[g][1] = 0.0f;
        }
    }
    #pragma unroll
    for (int g = 0; g < 4; ++g) {
        #pragma unroll
        for (int p = 0; p < 5; ++p) { pin2(wi[g][p]); pin2(wh[g][p]); }
        pin2(bias[g]);
    }

    float h = hp[(l * B + b) * H + j];
    float c = cp[(l * B + b) * H + j];
    // Seed own-h carry: layer l's first phase2 is kp2=l, reading parity
    // (l-1)&1 == (l+1)&1, row l+1, u=U-1.
    buf[(l + 1) & 1][U - 1][l + 1][j] = h;

    const bool is_st = (lidx < 10);           // wave0 l=0 primaries stage x
    float xcur[U], xnext[U];
    if (is_st) {
        #pragma unroll
        for (int u = 0; u < U; ++u)           // window 0 -> parity 1
            buf[1][u][0][j] = x[(size_t)u * BH + boff];
        #pragma unroll
        for (int u = 0; u < U; ++u) xcur[u] = x[(size_t)(U + u) * BH + boff];
    }
    __syncthreads();

    // x-projection accumulators (per u, per gate); live across barriers.
    v2f acc[U][4];

    // phase1 piece: x-projection of timestep u for interval k, reading row l
    // at parity par. All call sites use literal u (static acc indexing).
    auto phase1_u = [&](int k, int par, int u) {
        if ((unsigned)(k - l) < (unsigned)NWIN) {
            const float* xr = &buf[par][u][l][0];
            v4f q0 = *(const v4f*)(xr + 0);
            v4f q1 = *(const v4f*)(xr + 4);
            v2f q2 = *(const v2f*)(xr + 8);
            #pragma unroll
            for (int g = 0; g < 4; ++g) {
                v2f a = v2fma(wi[g][0], lo2(q0), bias[g]);
                a = v2fma(wi[g][1], hi2(q0), a);
                a = v2fma(wi[g][2], lo2(q1), a);
                a = v2fma(wi[g][3], hi2(q1), a);
                a = v2fma(wi[g][4], q2, a);
                acc[u][g] = a;
            }
        }
    };

    // fused(kp2): phase2(kp2) with phase1(kp2+1) pieces interleaved as
    // latency filler. phase2 writes parity wp=kp2&1; h-carry from rp=wp^1.
    // phase1(kp2+1) reads parity wp: row l written this interval by group
    // l-1 (same wave, in-order DS), or staged at start (row 0), or by the
    // other wave one epoch earlier (wave1 row 6; barrier-ordered).
    auto fused = [&](int kp2, int wp, int rp) {
        // Stage x window kp2+1 into parity wp BEFORE any phase1 read of it.
        if (is_st && (kp2 + 1) < NWIN) {
            #pragma unroll
            for (int u = 0; u < U; ++u) buf[wp][u][0][j] = xcur[u];
        }
        LDS_FENCE;
        // Prefetch x window kp2+2 (global latency spans the interval).
        if (is_st && (kp2 + 2) < NWIN) {
            #pragma unroll
            for (int u = 0; u < U; ++u)
                xnext[u] = x[(size_t)((kp2 + 2) * U + u) * BH + boff];
        }
        const unsigned w2 = (unsigned)(kp2 - l);
        const bool act2 = w2 < (unsigned)NWIN;
        v4f hq0 = {}, hq1 = {}; v2f hq2 = {};
        if (act2) {   // barrier-stable h-carry row: preload early
            const float* hr0 = &buf[rp][U - 1][l + 1][0];
            hq0 = *(const v4f*)(hr0 + 0);
            hq1 = *(const v4f*)(hr0 + 4);
            hq2 = *(const v2f*)(hr0 + 8);
        }
        float hv[U] = {};
        #pragma unroll
        for (int u = 0; u < U; ++u) {
            // 1) issue the critical h-row read first
            v4f q0 = hq0, q1 = hq1; v2f q2 = hq2;
            if (act2 && u > 0) {
                const float* hr = &buf[wp][u - 1][l + 1][0];
                q0 = *(const v4f*)(hr + 0);
                q1 = *(const v4f*)(hr + 4);
                q2 = *(const v2f*)(hr + 8);
            }
            // 2) independent filler: phase1(kp2+1) piece for timestep u-1
            if (u >= 1) phase1_u(kp2 + 1, wp, u - 1);
            // 3) recurrence chain for timestep u
            if (act2) {
                v2f aI = v2fma(wh[0][0], lo2(q0), acc[u][0]);
                v2f aF = v2fma(wh[1][0], lo2(q0), acc[u][1]);
                v2f aG = v2fma(wh[2][0], lo2(q0), acc[u][2]);
                v2f aO = v2fma(wh[3][0], lo2(q0), acc[u][3]);
                aI = v2fma(wh[0][1], hi2(q0), aI);
                aF = v2fma(wh[1][1], hi2(q0), aF);
                aG = v2fma(wh[2][1], hi2(q0), aG);
                aO = v2fma(wh[3][1], hi2(q0), aO);
                aI = v2fma(wh[0][2], lo2(q1), aI);
                aF = v2fma(wh[1][2], lo2(q1), aF);
                aG = v2fma(wh[2][2], lo2(q1), aG);
                aO = v2fma(wh[3][2], lo2(q1), aO);
                aI = v2fma(wh[0][3], hi2(q1), aI);
                aF = v2fma(wh[1][3], hi2(q1), aF);
                aG = v2fma(wh[2][3], hi2(q1), aG);
                aO = v2fma(wh[3][3], hi2(q1), aO);
                aI = v2fma(wh[0][4], q2, aI);
                aF = v2fma(wh[1][4], q2, aF);
                aG = v2fma(wh[2][4], q2, aG);
                aO = v2fma(wh[3][4], q2, aO);
                const float pI = aI[0] + aI[1];   // pre_i * -log2e
                const float pF = aF[0] + aF[1];   // pre_f * -log2e
                const float pG = aG[0] + aG[1];   // pre_g * -2log2e
                const float pO = aO[0] + aO[1];   // pre_o * -log2e
                // 7-trans activation (5 exp2 + 2 rcp), proven R5-R9:
                //   c' = [c*d2 + (1-Eg)*d1]/(d1*d2), d1=1+Ef, d2=(1+Ei)(1+Eg)
                //   h  = (1-Ec)/((1+Eo)(1+Ec)), Ec = e^-2c'
                const float Ei = exp2_f(pI);
                const float Ef = exp2_f(pF);
                const float Eg = exp2_f(pG);
                const float Eo = exp2_f(pO);
                const float d1 = 1.0f + Ef;
                const float e1 = 1.0f + Ei;
                const float e2 = 1.0f + Eg;
                const float d2 = e1 * e2;
                const float num = fmaf(c, d2, (1.0f - Eg) * d1);
                c = num * rcp_f(d1 * d2);
                const float Ec = exp2_f((2.0f * NL2E) * c);
                const float o1 = 1.0f + Eo;
                const float o2 = 1.0f + Ec;
                h = (1.0f - Ec) * rcp_f(o1 * o2);
                buf[wp][u][l + 1][j] = h;         // single b32; l=9 -> pad row
                hv[u] = h;
            }
            LDS_FENCE;   // pin write(u) before reads at body u+1 / tail
        }
        // tail filler: phase1(kp2+1) piece for timestep U-1
        phase1_u(kp2 + 1, wp, U - 1);
        if (act2 && l == L - 1) {             // batched out-stores (dups benign)
            const int t0 = (int)w2 * U;
            #pragma unroll
            for (int u = 0; u < U; ++u)
                out[(size_t)(t0 + u) * BH + boff] = hv[u];
        }
        if (is_st) {
            #pragma unroll
            for (int u = 0; u < U; ++u) xcur[u] = xnext[u];
        }
    };

    // wave0 runs fused(k) while wave1 runs fused(k-1): wave1's row-6 phase1
    // reads are then one epoch behind wave0's row-6 writes (barrier-ordered).
    if (wv == 0) {
        // prologue: plain phase1(0) from parity 1 (slot -1; only l=0 active)
        phase1_u(0, 1, 0); phase1_u(0, 1, 1); phase1_u(0, 1, 2); phase1_u(0, 1, 3);
        for (int kk = 0; kk < NINT + 1; kk += 2) {   // literal parities
            fused(kk, 0, 1);
            __syncthreads();
            fused(kk + 1, 1, 0);
            __syncthreads();
        }
    } else {
        for (int kk = 0; kk < NINT + 1; kk += 2) {
            fused(kk - 1, 1, 0);   // epoch n computes phase2(n-1), phase1(n)
            __syncthreads();
            fused(kk, 0, 1);
            __syncthreads();
        }
    }

    hn[(l * B + b) * H + j] = h;   // dup lanes store identical values
    cn[(l * B + b) * H + j] = c;
}

} // namespace

extern "C" void kernel_launch(void* const* d_in, const int* in_sizes, int n_in,
                              void* d_out, int out_size, void* d_ws, size_t ws_size,
                              hipStream_t stream) {
    (void)in_sizes; (void)n_in; (void)d_ws; (void)ws_size; (void)out_size;
    const float* x   = (const float*)d_in[0];
    const float* hp  = (const float*)d_in[1];
    const float* cp  = (const float*)d_in[2];
    const float* Wih = (const float*)d_in[3];
    const float* Whh = (const float*)d_in[4];
    const float* bih = (const float*)d_in[5];
    const float* bhh = (const float*)d_in[6];

    float* out = (float*)d_out;
    float* hn  = out + (size_t)T * B * H;
    float* cn  = hn + (size_t)L * B * H;

    lstm_pipeline<<<dim3(B), dim3(NTHREADS), 0, stream>>>(
        x, hp, cp, Wih, Whh, bih, bhh, out, hn, cn);
}

// Round 11
// 455.773 us; speedup vs baseline: 1.1605x; 1.1605x over previous
//
#include <hip/hip_runtime.h>

namespace {

constexpr int T = 1024;
constexpr int B = 1024;
constexpr int L = 10;
constexpr int H = 10;
constexpr int NTHREADS = 128;      // 2 waves: wave0 = layers 0-5, wave1 = layers 6-9
constexpr int U = 8;               // timesteps per interval (R11: 4 -> 8)
constexpr int NWIN = T / U;        // 128 windows
constexpr int NINT = NWIN + L - 1; // 137 intervals
constexpr int BH = B * H;
constexpr int ROWP = 12;           // compact row: 10 real floats + 2 pad (48 B)

using v2f = __attribute__((ext_vector_type(2))) float;
using v4f = __attribute__((ext_vector_type(4))) float;

__device__ __forceinline__ v2f v2fma(v2f a, v2f b, v2f c) {
    return __builtin_elementwise_fma(a, b, c);   // v_pk_fma_f32
}
__device__ __forceinline__ void pin2(v2f& v) { asm volatile("" : "+v"(v)); }
__device__ __forceinline__ float rcp_f(float x) { return __builtin_amdgcn_rcpf(x); }
// bare v_exp_f32 (2^x) - weights are pre-scaled by +/-log2e so no mul needed
__device__ __forceinline__ float exp2_f(float x) {
    float r; asm("v_exp_f32 %0, %1" : "=v"(r) : "v"(x)); return r;
}
__device__ __forceinline__ v2f lo2(v4f q) { return __builtin_shufflevector(q, q, 0, 1); }
__device__ __forceinline__ v2f hi2(v4f q) { return __builtin_shufflevector(q, q, 2, 3); }
#define LDS_FENCE asm volatile("" ::: "memory")

__global__
__attribute__((amdgpu_flat_work_group_size(NTHREADS, NTHREADS)))
__attribute__((amdgpu_waves_per_eu(2)))   // cap VGPR at 256; 2 waves/SIMD resident
void lstm_pipeline(const float* __restrict__ x,    // [T,B,H]
                   const float* __restrict__ hp,   // [L,B,H]
                   const float* __restrict__ cp,   // [L,B,H]
                   const float* __restrict__ Wih,  // [L,4H,H]
                   const float* __restrict__ Whh,  // [L,4H,H]
                   const float* __restrict__ bih,  // [L,4H]
                   const float* __restrict__ bhh,  // [L,4H]
                   float* __restrict__ out,        // [T,B,H]
                   float* __restrict__ hn,         // [L,B,H]
                   float* __restrict__ cn)         // [L,B,H]
{
    // [parity][u][row][compact]; row r = input of layer r (r=0: x, r=l+1:
    // layer-l output). 12-float row stride: layer groups hit disjoint banks.
    __shared__ __align__(16) float buf[2][U][L + 1][ROWP];   // 8448 B

    const int tid = threadIdx.x;
    const int wv = tid >> 6;
    const int ln = tid & 63;
    // (l,j) mapping, proven in prior rounds. Dup lanes repeat valid items of
    // the same wave -> identical values/addresses, benign.
    int lidx;
    if (wv == 0) lidx = (ln < 60) ? ln : (ln - 10);              // dup l=5,j=0..3
    else         lidx = (ln < 40) ? (60 + ln) : (90 + (ln - 40) % 10);  // dup l=9
    const int l = lidx / 10;
    const int j = lidx % 10;
    const int b = blockIdx.x;
    const int boff = b * H + j;

    // ---- weights -> registers, k-pair packed, exp2-prescaled per gate ----
    // wi[g][p] = (W[g-row, 2p], W[g-row, 2p+1]) * scale_g.
    // Gate order g = 0:i 1:f 2:g 3:o; scales: i,f,o -> -log2e, g -> -2*log2e.
    const float NL2E = -1.44269504088896340736f;
    v2f wi[4][5], wh[4][5], bias[4];
    {
        const float* WiL = Wih + (size_t)l * 4 * H * H;
        const float* WhL = Whh + (size_t)l * 4 * H * H;
        const int bo = l * 4 * H;
        #pragma unroll
        for (int g = 0; g < 4; ++g) {
            const float s = (g == 2) ? 2.0f * NL2E : NL2E;
            const float* wr = WiL + (size_t)(g * H + j) * H;
            const float* hr = WhL + (size_t)(g * H + j) * H;
            #pragma unroll
            for (int p = 0; p < 5; ++p) {
                wi[g][p][0] = wr[2 * p] * s; wi[g][p][1] = wr[2 * p + 1] * s;
                wh[g][p][0] = hr[2 * p] * s; wh[g][p][1] = hr[2 * p + 1] * s;
            }
            bias[g][0] = (bih[bo + g * H + j] + bhh[bo + g * H + j]) * s;
            bias[g][1] = 0.0f;
        }
    }
    #pragma unroll
    for (int g = 0; g < 4; ++g) {
        #pragma unroll
        for (int p = 0; p < 5; ++p) { pin2(wi[g][p]); pin2(wh[g][p]); }
        pin2(bias[g]);
    }

    float h = hp[(l * B + b) * H + j];
    float c = cp[(l * B + b) * H + j];
    // Seed own-h row for first active interval k=l (P2(l) u=0 reads parity
    // (l-1)&1 == (l+1)&1, row l+1, u=U-1).
    buf[(l + 1) & 1][U - 1][l + 1][j] = h;

    const bool is_st = (lidx < 10);           // wave0 l=0 primaries stage x
    float xcur[U], xnext[U];
    if (is_st) {
        #pragma unroll
        for (int u = 0; u < U; ++u)           // window 0 -> parity 1 (rp of k=0)
            buf[1][u][0][j] = x[(size_t)u * BH + boff];
        #pragma unroll
        for (int u = 0; u < U; ++u) xcur[u] = x[(size_t)(U + u) * BH + boff];
    }
    __syncthreads();

    // x-projection accumulators (per u, per gate); wave1: live across barrier.
    v2f acc[U][4];

    auto prefetchx = [&](int k) {
        if (is_st && (k + 2) < NWIN) {
            #pragma unroll
            for (int u = 0; u < U; ++u)
                xnext[u] = x[(size_t)((k + 2) * U + u) * BH + boff];
        }
    };

    // phase1(k): x-projections for window k-l, reading row l slot k-1 (parity rp).
    auto phase1 = [&](int k, int rp) {
        const unsigned w = (unsigned)(k - l);
        if (w < (unsigned)NWIN) {
            #pragma unroll
            for (int u = 0; u < U; ++u) {
                const float* xr = &buf[rp][u][l][0];
                v4f q0 = *(const v4f*)(xr + 0);
                v4f q1 = *(const v4f*)(xr + 4);
                v2f q2 = *(const v2f*)(xr + 8);
                #pragma unroll
                for (int g = 0; g < 4; ++g) {
                    v2f a = v2fma(wi[g][0], lo2(q0), bias[g]);
                    a = v2fma(wi[g][1], hi2(q0), a);
                    a = v2fma(wi[g][2], lo2(q1), a);
                    a = v2fma(wi[g][3], hi2(q1), a);
                    a = v2fma(wi[g][4], q2, a);
                    acc[u][g] = a;
                }
            }
        }
    };

    // phase2(k): recurrence for window k-l; writes slot k (parity wp),
    // u=0 h-row from slot k-1 (parity rp). Consumes acc from phase1(k).
    auto phase2 = [&](int k, int wp, int rp) {
        const unsigned w = (unsigned)(k - l);
        if (w < (unsigned)NWIN) {
            // Barrier-stable u=0 h-row: preload for latency cover.
            const float* hr0 = &buf[rp][U - 1][l + 1][0];
            v4f hq0 = *(const v4f*)(hr0 + 0);
            v4f hq1 = *(const v4f*)(hr0 + 4);
            v2f hq2 = *(const v2f*)(hr0 + 8);
            float hv[U];
            #pragma unroll
            for (int u = 0; u < U; ++u) {
                v4f q0, q1; v2f q2;
                if (u == 0) { q0 = hq0; q1 = hq1; q2 = hq2; }
                else {
                    const float* hr = &buf[wp][u - 1][l + 1][0];
                    q0 = *(const v4f*)(hr + 0);
                    q1 = *(const v4f*)(hr + 4);
                    q2 = *(const v2f*)(hr + 8);
                }
                v2f aI = v2fma(wh[0][0], lo2(q0), acc[u][0]);
                v2f aF = v2fma(wh[1][0], lo2(q0), acc[u][1]);
                v2f aG = v2fma(wh[2][0], lo2(q0), acc[u][2]);
                v2f aO = v2fma(wh[3][0], lo2(q0), acc[u][3]);
                aI = v2fma(wh[0][1], hi2(q0), aI);
                aF = v2fma(wh[1][1], hi2(q0), aF);
                aG = v2fma(wh[2][1], hi2(q0), aG);
                aO = v2fma(wh[3][1], hi2(q0), aO);
                aI = v2fma(wh[0][2], lo2(q1), aI);
                aF = v2fma(wh[1][2], lo2(q1), aF);
                aG = v2fma(wh[2][2], lo2(q1), aG);
                aO = v2fma(wh[3][2], lo2(q1), aO);
                aI = v2fma(wh[0][3], hi2(q1), aI);
                aF = v2fma(wh[1][3], hi2(q1), aF);
                aG = v2fma(wh[2][3], hi2(q1), aG);
                aO = v2fma(wh[3][3], hi2(q1), aO);
                aI = v2fma(wh[0][4], q2, aI);
                aF = v2fma(wh[1][4], q2, aF);
                aG = v2fma(wh[2][4], q2, aG);
                aO = v2fma(wh[3][4], q2, aO);
                const float pI = aI[0] + aI[1];   // pre_i * -log2e
                const float pF = aF[0] + aF[1];   // pre_f * -log2e
                const float pG = aG[0] + aG[1];   // pre_g * -2log2e
                const float pO = aO[0] + aO[1];   // pre_o * -log2e
                // 7-trans activation block (5 exp2 + 2 rcp), same as R5-R9:
                //   c' = [c*d2 + (1-Eg)*d1] / (d1*d2), d1=1+Ef, d2=(1+Ei)(1+Eg)
                //   h  = (1-Ec) / ((1+Eo)(1+Ec)), Ec = e^-2c'
                const float Ei = exp2_f(pI);
                const float Ef = exp2_f(pF);
                const float Eg = exp2_f(pG);
                const float Eo = exp2_f(pO);
                const float d1 = 1.0f + Ef;
                const float e1 = 1.0f + Ei;
                const float e2 = 1.0f + Eg;
                const float d2 = e1 * e2;
                const float num = fmaf(c, d2, (1.0f - Eg) * d1);
                c = num * rcp_f(d1 * d2);
                const float Ec = exp2_f((2.0f * NL2E) * c);
                const float o1 = 1.0f + Eo;
                const float o2 = 1.0f + Ec;
                h = (1.0f - Ec) * rcp_f(o1 * o2);
                buf[wp][u][l + 1][j] = h;         // single b32 write; l=9 -> pad row
                hv[u] = h;
            }
            if (l == L - 1) {                 // batched out-stores (dups benign)
                const int t0 = (int)w * U;
                #pragma unroll
                for (int u = 0; u < U; ++u)
                    out[(size_t)(t0 + u) * BH + boff] = hv[u];
            }
        }
    };

    auto stagex = [&](int k, int wp) {
        if (is_st && (k + 1) < NWIN) {
            #pragma unroll
            for (int u = 0; u < U; ++u) buf[wp][u][0][j] = xcur[u];
            #pragma unroll
            for (int u = 0; u < U; ++u) xcur[u] = xnext[u];
        }
    };

    // Anti-aligned schedule (proven in R6/R9): wave0 runs [P1(k); P2(k)], wave1
    // runs [P2(k-1); P1(k)] so one wave's dense dot-product phase overlaps the
    // other's latency-bound recurrence. Cross-wave dep (row 6): wave1 P1(k)
    // reads what wave0 P2(k-1) wrote before the previous barrier. Within a
    // region the compiler is free to interleave P1/P2 (no order pinning).
    if (wv == 0) {
        for (int kk = 0; kk < NINT + 1; kk += 2) {   // literal parities
            prefetchx(kk);
            phase1(kk, 1);        LDS_FENCE;
            phase2(kk, 0, 1);     LDS_FENCE;
            stagex(kk, 0);
            __syncthreads();
            prefetchx(kk + 1);
            phase1(kk + 1, 0);    LDS_FENCE;
            phase2(kk + 1, 1, 0); LDS_FENCE;
            stagex(kk + 1, 1);
            __syncthreads();
        }
    } else {
        for (int kk = 0; kk < NINT + 1; kk += 2) {
            phase2(kk - 1, 1, 0); LDS_FENCE;   // slot kk-1 parity 1, u0 from parity 0
            phase1(kk, 1);
            __syncthreads();
            phase2(kk, 0, 1);     LDS_FENCE;
            phase1(kk + 1, 0);
            __syncthreads();
        }
    }

    hn[(l * B + b) * H + j] = h;   // dup lanes store identical values
    cn[(l * B + b) * H + j] = c;
}

} // namespace

extern "C" void kernel_launch(void* const* d_in, const int* in_sizes, int n_in,
                              void* d_out, int out_size, void* d_ws, size_t ws_size,
                              hipStream_t stream) {
    (void)in_sizes; (void)n_in; (void)d_ws; (void)ws_size; (void)out_size;
    const float* x   = (const float*)d_in[0];
    const float* hp  = (const float*)d_in[1];
    const float* cp  = (const float*)d_in[2];
    const float* Wih = (const float*)d_in[3];
    const float* Whh = (const float*)d_in[4];
    const float* bih = (const float*)d_in[5];
    const float* bhh = (const float*)d_in[6];

    float* out = (float*)d_out;
    float* hn  = out + (size_t)T * B * H;
    float* cn  = hn + (size_t)L * B * H;

    lstm_pipeline<<<dim3(B), dim3(NTHREADS), 0, stream>>>(
        x, hp, cp, Wih, Whh, bih, bhh, out, hn, cn);
}